// Round 18
// baseline (115.018 us; speedup 1.0000x reference)
//
#include <hip/hip_runtime.h>
#include <hip/hip_fp16.h>

#define N_NODES 50000
#define DIM 64
#define CB 391          // buckets = ceil(N/128); bucket = dst >> 7
#define PBLK 131        // partition blocks
#define PEPB 6144       // edges per partition block (512 thr x 12)
#define EPT 12          // edges per thread (register-staged)
#define RUNW 48         // slots per (block,bucket) run = 192 B (mean 15.7, +8 sd)
#define CAPB (PBLK * RUNW)   // 6288 slots per bucket
#define BINCAP 64       // per-node LDS edge slots (deg mean 16 sd 4 -> z=12)

typedef _Float16 half8 __attribute__((ext_vector_type(8)));
typedef _Float16 half4v __attribute__((ext_vector_type(4)));
typedef float floatx4 __attribute__((ext_vector_type(4)));

// Workspace byte offsets (64B-aligned).
#define WS_COARSE  0                          // CB*CAPB*4 = 9,834,432
#define WS_CNT     9834432                    // PBLK*CB*4 = 204,884 -> 204,928
#define WS_XH      (WS_CNT + 204928)          // N*DIM f16 = 6,400,000
#define WS_WT      (WS_XH + 6400000)          // DIM*DIM f16 = 8,192

// ---------------------------------------------------------------------------
// Prep (one dispatch, 512 thr, == R16).  Blocks [0,131): single-pass
// register-staged partition into DETERMINISTIC per-(block,bucket) runs:
//   coarse[bk*6288 + b*48 + r], cnt[b][bk]
// -> no global cursor, no memset, no global atomics.  Blocks [131,1694):
// x -> fp16.  Last block: W^T fp16.  Producer->consumer coherence via the
// KERNEL BOUNDARY (grid.sync() inside one kernel is NOT sufficient across
// XCD L2s — R14 failed with absmax 22).
// ---------------------------------------------------------------------------
__global__ void __launch_bounds__(512) prep_kernel(
        const float* __restrict__ x, const float* __restrict__ W,
        const int* __restrict__ edge_src, const int* __restrict__ edge_dst,
        unsigned int* __restrict__ coarse, int* __restrict__ cnt,
        _Float16* __restrict__ xh, _Float16* __restrict__ wt, int E) {
    int b = blockIdx.x, t = threadIdx.x;
    if (b < PBLK) {
        __shared__ int lhist[CB];
        for (int i = t; i < CB; i += 512) lhist[i] = 0;
        __syncthreads();

        int base = b * PEPB;
        unsigned int pk[EPT];
        int bk[EPT];
        #pragma unroll
        for (int j = 0; j < EPT; ++j) {
            int e = base + j * 512 + t;       // coalesced
            bk[j] = -1;
            if (e < E) {
                int s = edge_src[e];
                int d = edge_dst[e];
                bk[j] = d >> 7;
                pk[j] = ((unsigned int)s << 7) | (unsigned int)(d & 127);
                atomicAdd(&lhist[bk[j]], 1);
            }
        }
        __syncthreads();
        for (int i = t; i < CB; i += 512) {
            cnt[(size_t)b * CB + i] = lhist[i];
            lhist[i] = 0;                     // reuse as running cursor
        }
        __syncthreads();
        #pragma unroll
        for (int j = 0; j < EPT; ++j) {
            if (bk[j] >= 0) {
                int r = atomicAdd(&lhist[bk[j]], 1);
                coarse[(size_t)bk[j] * CAPB + b * RUNW + r] = pk[j];
            }
        }
    } else if (b < PBLK + 1563) {
        int i = (b - PBLK) * 512 + t;         // one float4 per thread
        if (i < N_NODES * DIM / 4) {
            float4 v = reinterpret_cast<const float4*>(x)[i];
            half4v h = { (_Float16)v.x, (_Float16)v.y, (_Float16)v.z, (_Float16)v.w };
            reinterpret_cast<half4v*>(xh)[i] = h;
        }
    } else {
        #pragma unroll
        for (int i = 0; i < 8; ++i) {         // W^T: wt[n*64+k] = W[k*64+n]
            int idx = t * 8 + i;
            int n = idx >> 6, k = idx & 63;
            wt[idx] = (_Float16)W[k * DIM + n];
        }
    }
}

// ---------------------------------------------------------------------------
// Fused bin + gather + project — one 512-thread block per 128-node bucket
// (grid 391).  Gather happens DIRECTLY in MFMA A-fragment layout: wave =
// 16 nodes x 4 lanes; lane (m=lane&15, q=lane>>4) accumulates the halves
// its A-frags need (k = q*8+j and 32+q*8+j -> two 16 B loads per edge per
// lane, same 128 B/edge total).  No pl transpose tile (34.8 KB LDS saved,
// one fewer barrier); acc converts fp32->f16 in registers into a0/a1.
//  1. lcnt staged in LDS; one coalesced scan over the bucket's 6288 slots
//     (validity r < lcnt[run]); matching edges -> per-node ushort slot
//     arrays via LDS atomic.
//  2. per-lane gather over its own node's list (4 lanes share the list ->
//     broadcast ds_read), 4 edges / 8 loads in flight, fp32 accumulate,
//     residual from xh.
//  3. 2x mfma_f32_16x16x32_f16 per N-tile (4 tiles), bias+/deg+ReLU -> out.
// Numerics identical to R16 (same chunking, same edge order) -> absmax
// must remain exactly 0.125.
// ---------------------------------------------------------------------------
__global__ void __launch_bounds__(512) fused_kernel(
        const _Float16* __restrict__ xh,
        const _Float16* __restrict__ wt,
        const float* __restrict__ bias,
        const float* __restrict__ deg,
        const int* __restrict__ cnt,
        const unsigned int* __restrict__ coarse,
        float* __restrict__ out) {
    __shared__ unsigned short sedges[128 * BINCAP];  // 16 KB
    __shared__ int cur[128];
    __shared__ int lcnt[PBLK];

    int t = threadIdx.x;
    int bucket = blockIdx.x;
    int nb = bucket * 128;

    if (t < 128) cur[t] = 0;
    if (t >= 128 && t < 128 + PBLK)
        lcnt[t - 128] = cnt[(size_t)(t - 128) * CB + bucket];
    __syncthreads();

    // --- 1. single coalesced scan over the bucket's 131 runs ---
    const unsigned int* cbk = coarse + (size_t)bucket * CAPB;
    for (int i = t; i < CAPB; i += 512) {
        int run = i / RUNW;                 // magic-multiply by compiler
        int r = i - run * RUNW;
        if (r < lcnt[run]) {
            unsigned int e = cbk[i];
            int loc = (int)(e & 127u);
            int p = atomicAdd(&cur[loc], 1);
            sedges[loc * BINCAP + p] = (unsigned short)(e >> 7);
        }
    }
    __syncthreads();

    // --- 2+3. gather in A-layout, then MFMA ---
    int wv = t >> 6;          // wave 0..7 -> nodes lbase..lbase+15
    int lane = t & 63;
    int m = lane & 15;
    int q = lane >> 4;
    int lbase = wv * 16;
    int loc = lbase + m;
    int node = nb + loc;

    float acc0[8], acc1[8];
    #pragma unroll
    for (int j = 0; j < 8; ++j) { acc0[j] = 0.f; acc1[j] = 0.f; }

    const unsigned short* bp = &sedges[loc * BINCAP];
    int ct = cur[loc];                      // 0 for nodes >= N (no edges)
    int k = 0;
    for (; k + 4 <= ct; k += 4) {           // 4 edges, 8 loads in flight
        int sid[4];
        #pragma unroll
        for (int u = 0; u < 4; ++u) sid[u] = (int)bp[k + u];
        half8 v0[4], v1[4];
        #pragma unroll
        for (int u = 0; u < 4; ++u) {
            const _Float16* rp = xh + (size_t)sid[u] * DIM + q * 8;
            v0[u] = *reinterpret_cast<const half8*>(rp);
            v1[u] = *reinterpret_cast<const half8*>(rp + 32);
        }
        #pragma unroll
        for (int u = 0; u < 4; ++u) {
            #pragma unroll
            for (int j = 0; j < 8; ++j) {
                acc0[j] += (float)v0[u][j];
                acc1[j] += (float)v1[u][j];
            }
        }
    }
    for (; k < ct; ++k) {
        const _Float16* rp = xh + (size_t)bp[k] * DIM + q * 8;
        half8 v0 = *reinterpret_cast<const half8*>(rp);
        half8 v1 = *reinterpret_cast<const half8*>(rp + 32);
        #pragma unroll
        for (int j = 0; j < 8; ++j) {
            acc0[j] += (float)v0[j];
            acc1[j] += (float)v1[j];
        }
    }

    // Residual (node rows >= N read garbage inside ws; their C rows are
    // gated at the write, and MFMA row m feeds only C row m).
    {
        const _Float16* rp = xh + (size_t)node * DIM + q * 8;
        half8 r0 = *reinterpret_cast<const half8*>(rp);
        half8 r1 = *reinterpret_cast<const half8*>(rp + 32);
        #pragma unroll
        for (int j = 0; j < 8; ++j) {
            acc0[j] += (float)r0[j];
            acc1[j] += (float)r1[j];
        }
    }

    half8 a0, a1;
    #pragma unroll
    for (int j = 0; j < 8; ++j) { a0[j] = (_Float16)acc0[j]; a1[j] = (_Float16)acc1[j]; }

    floatx4 acc4[4];
    #pragma unroll
    for (int tt = 0; tt < 4; ++tt) {
        half8 b0 = *reinterpret_cast<const half8*>(wt + (size_t)(tt * 16 + m) * DIM + q * 8);
        half8 b1 = *reinterpret_cast<const half8*>(wt + (size_t)(tt * 16 + m) * DIM + q * 8 + 32);
        floatx4 cfrag = {0.f, 0.f, 0.f, 0.f};
        cfrag = __builtin_amdgcn_mfma_f32_16x16x32_f16(a0, b0, cfrag, 0, 0, 0);
        cfrag = __builtin_amdgcn_mfma_f32_16x16x32_f16(a1, b1, cfrag, 0, 0, 0);
        acc4[tt] = cfrag;
    }

    #pragma unroll
    for (int r = 0; r < 4; ++r) {
        int row = q * 4 + r;
        int onode = nb + lbase + row;
        if (onode < N_NODES) {
            float inv = 1.0f / deg[onode];
            #pragma unroll
            for (int tt = 0; tt < 4; ++tt) {
                float v = (acc4[tt][r] + bias[tt * 16 + m]) * inv;
                out[(size_t)onode * DIM + tt * 16 + m] = fmaxf(v, 0.f);
            }
        }
    }
}

extern "C" void kernel_launch(void* const* d_in, const int* in_sizes, int n_in,
                              void* d_out, int out_size, void* d_ws, size_t ws_size,
                              hipStream_t stream) {
    const float* x        = (const float*)d_in[0];
    const float* weight   = (const float*)d_in[1];
    const float* bias     = (const float*)d_in[2];
    const float* node_deg = (const float*)d_in[3];
    const int*   edge_src = (const int*)d_in[4];
    const int*   edge_dst = (const int*)d_in[5];
    float* out = (float*)d_out;
    int E = in_sizes[4];

    char* ws = (char*)d_ws;
    unsigned int* coarse = (unsigned int*)(ws + WS_COARSE);
    int*          cnt    = (int*)(ws + WS_CNT);
    _Float16*     xh     = (_Float16*)(ws + WS_XH);
    _Float16*     wt     = (_Float16*)(ws + WS_WT);

    prep_kernel<<<PBLK + 1563 + 1, 512, 0, stream>>>(
        x, weight, edge_src, edge_dst, coarse, cnt, xh, wt, E);

    fused_kernel<<<CB, 512, 0, stream>>>(
        xh, wt, bias, node_deg, cnt, coarse, out);
}

// Round 19
// 114.083 us; speedup vs baseline: 1.0082x; 1.0082x over previous
//
#include <hip/hip_runtime.h>
#include <hip/hip_fp16.h>

#define N_NODES 50000
#define DIM 64
#define CB 391          // coarse buckets = ceil(N/128); bucket = dst >> 7
#define CAP 2560        // per-bucket capacity (mean 2046, sd ~45 -> +11 sd)
#define EPT 12          // edges per thread in partition (register-staged)
#define EB (512 * EPT)  // 6144 edges per partition block -> 131 blocks
#define BINCAP 64       // per-node LDS edge slots (deg: mean 16 sd 4 -> z=12)
#define PLW 68          // pooled LDS row stride in floats (+4: bank spread)

typedef _Float16 half8 __attribute__((ext_vector_type(8)));
typedef _Float16 half4v __attribute__((ext_vector_type(4)));
typedef float floatx4 __attribute__((ext_vector_type(4)));

// Workspace byte offsets (16B-aligned).
#define WS_CURSOR  0                          // CB ints (2 KB reserved)
#define WS_COARSE  2048                       // CB*CAP uint = 4,003,840
#define WS_XH      (WS_COARSE + 4003840)      // N*DIM f16 = 6,400,000
#define WS_WT      (WS_XH + 6400000)          // DIM*DIM f16 = 8,192

// ---------------------------------------------------------------------------
// Prep (merged, 512 thr): blocks [0,pa): SINGLE-PASS partition — edges are
// staged in registers (EPT=12/thread), so src/dst are read exactly once;
// hist -> reserve -> scatter all from registers.  Blocks [pa, pa+1563):
// x -> fp16.  Last block: W^T fp16.  Edge packed as (src<<7)|(dst&127).
// Producer->consumer coherence relies on the KERNEL BOUNDARY (grid.sync()
// inside one kernel is NOT sufficient across XCD L2s — R14, absmax 22).
// ---------------------------------------------------------------------------
__global__ void __launch_bounds__(512) prep_kernel(
        const float* __restrict__ x, const float* __restrict__ W,
        const int* __restrict__ edge_src, const int* __restrict__ edge_dst,
        int* __restrict__ cursor, unsigned int* __restrict__ coarse,
        _Float16* __restrict__ xh, _Float16* __restrict__ wt,
        int E, int pa) {
    int b = blockIdx.x, t = threadIdx.x;
    if (b < pa) {
        __shared__ int lhist[CB];
        __shared__ int lbase[CB];
        for (int i = t; i < CB; i += 512) lhist[i] = 0;
        __syncthreads();

        int base = b * EB;
        unsigned int pk[EPT];
        int bk[EPT];
        #pragma unroll
        for (int j = 0; j < EPT; ++j) {
            int e = base + j * 512 + t;       // coalesced
            bk[j] = -1;
            if (e < E) {
                int s = edge_src[e];
                int d = edge_dst[e];
                bk[j] = d >> 7;
                pk[j] = ((unsigned int)s << 7) | (unsigned int)(d & 127);
                atomicAdd(&lhist[bk[j]], 1);
            }
        }
        __syncthreads();
        for (int i = t; i < CB; i += 512) {
            lbase[i] = atomicAdd(&cursor[i], lhist[i]);
            lhist[i] = 0;
        }
        __syncthreads();
        #pragma unroll
        for (int j = 0; j < EPT; ++j) {
            if (bk[j] >= 0) {
                int r = atomicAdd(&lhist[bk[j]], 1);
                coarse[(size_t)bk[j] * CAP + lbase[bk[j]] + r] = pk[j];
            }
        }
    } else if (b < pa + 1563) {
        int i = (b - pa) * 512 + t;           // one float4 per thread
        if (i < N_NODES * DIM / 4) {
            float4 v = reinterpret_cast<const float4*>(x)[i];
            half4v h = { (_Float16)v.x, (_Float16)v.y, (_Float16)v.z, (_Float16)v.w };
            reinterpret_cast<half4v*>(xh)[i] = h;
        }
    } else {
        #pragma unroll
        for (int i = 0; i < 8; ++i) {         // W^T: wt[n*64+k] = W[k*64+n]
            int idx = t * 8 + i;
            int n = idx >> 6, k = idx & 63;
            wt[idx] = (_Float16)W[k * DIM + n];
        }
    }
}

// ---------------------------------------------------------------------------
// Fused bin + gather + project (R13 verbatim — measured best, 112.0 µs).
// Grid 784; block b handles half half=(b>>3)&1 of bucket (b>>4)*8+(b&7)
// (sibling pair (b,b^8) -> same XCD under round-robin dispatch: bucket list
// fetched into one L2).
//  1. ONE scan pass over the packed bucket list: matching edges drop into
//     per-node slot arrays (sedges[bin*64+slot], slot via LDS int atomic).
//     No hist pass, no prefix scan.  deg max ~35 << 64 cap.
//  2. 32 groups x 8 lanes, 2 nodes/group: 8 edges in flight, half8 fp16
//     gather, fp32 register accumulate, residual from xh (L2-hot), one
//     ds_write per row chunk into the stride-68 fp32 tile.
//  3. 4 waves x 16 nodes: fp32->f16 A-frags from the tile, B-frags from
//     W^T, 2x mfma_f32_16x16x32_f16 per N-tile, bias + /deg + ReLU -> out.
// ---------------------------------------------------------------------------
__global__ void __launch_bounds__(256) fused_kernel(
        const _Float16* __restrict__ xh,
        const _Float16* __restrict__ wt,
        const float* __restrict__ bias,
        const float* __restrict__ deg,
        const int* __restrict__ cursor,
        const unsigned int* __restrict__ coarse,
        float* __restrict__ out) {
    __shared__ int sedges[64 * BINCAP];    // 16 KB
    __shared__ float pl[64 * PLW];         // 17.4 KB
    __shared__ int cur[64];

    int t = threadIdx.x;
    int b = blockIdx.x;
    int bucket = (b >> 4) * 8 + (b & 7);   // pair (b, b^8) -> same bucket+XCD
    int half = (b >> 3) & 1;
    if (bucket >= CB) return;              // block-uniform early-out
    int nb = bucket * 128 + half * 64;     // global node base for this block
    int cnt = cursor[bucket];
    const unsigned int* cbk = coarse + (size_t)bucket * CAP;

    if (t < 64) cur[t] = 0;
    __syncthreads();

    // --- 1. one-pass binned scatter ---
    for (int i = t; i < cnt; i += 256) {
        unsigned int e = cbk[i];
        int loc = (int)(e & 127u);
        if ((loc >> 6) == half) {
            int bin = loc & 63;
            int p = atomicAdd(&cur[bin], 1);
            sedges[bin * BINCAP + p] = (int)(e >> 7);
        }
    }
    __syncthreads();

    // --- 2. gather: 32 groups of 8 lanes, 2 nodes per group, 8 in flight ---
    int g = t >> 3;          // group 0..31
    int c = t & 7;           // half8 chunk within the 64-half row
    #pragma unroll
    for (int pass = 0; pass < 2; ++pass) {
        int loc = g + pass * 32;
        int node = nb + loc;
        float acc[8];
        #pragma unroll
        for (int j = 0; j < 8; ++j) acc[j] = 0.f;
        const int* bp = &sedges[loc * BINCAP];
        int ct = cur[loc];                  // 0 for nodes >= N (no edges)
        int k = 0;
        for (; k + 8 <= ct; k += 8) {       // 8 edges in flight
            int sid[8];
            #pragma unroll
            for (int u = 0; u < 8; ++u) sid[u] = bp[k + u];
            half8 v[8];
            #pragma unroll
            for (int u = 0; u < 8; ++u)
                v[u] = *reinterpret_cast<const half8*>(xh + (size_t)sid[u] * DIM + c * 8);
            #pragma unroll
            for (int u = 0; u < 8; ++u) {
                #pragma unroll
                for (int j = 0; j < 8; ++j) acc[j] += (float)v[u][j];
            }
        }
        for (; k + 4 <= ct; k += 4) {       // 4-wide tail
            int sid[4];
            #pragma unroll
            for (int u = 0; u < 4; ++u) sid[u] = bp[k + u];
            half8 v[4];
            #pragma unroll
            for (int u = 0; u < 4; ++u)
                v[u] = *reinterpret_cast<const half8*>(xh + (size_t)sid[u] * DIM + c * 8);
            #pragma unroll
            for (int u = 0; u < 4; ++u) {
                #pragma unroll
                for (int j = 0; j < 8; ++j) acc[j] += (float)v[u][j];
            }
        }
        for (; k < ct; ++k) {
            int s0 = bp[k];
            half8 v0 = *reinterpret_cast<const half8*>(xh + (size_t)s0 * DIM + c * 8);
            #pragma unroll
            for (int j = 0; j < 8; ++j) acc[j] += (float)v0[j];
        }
        if (node < N_NODES) {
            half8 r = *reinterpret_cast<const half8*>(
                xh + (size_t)node * DIM + c * 8);
            float* p = &pl[loc * PLW + c * 8];
            #pragma unroll
            for (int j = 0; j < 8; ++j) p[j] = acc[j] + (float)r[j];
        }
    }
    __syncthreads();

    // --- 3. MFMA projection: wave wv handles nodes lbase..lbase+15 ---
    int wv = t >> 6;
    int lane = t & 63;
    int m = lane & 15;
    int q = lane >> 4;
    int lbase = wv * 16;

    const float* ap = &pl[(lbase + m) * PLW];
    half8 a0, a1;
    #pragma unroll
    for (int j = 0; j < 8; ++j) a0[j] = (_Float16)ap[q * 8 + j];
    #pragma unroll
    for (int j = 0; j < 8; ++j) a1[j] = (_Float16)ap[32 + q * 8 + j];

    floatx4 acc4[4];
    #pragma unroll
    for (int tt = 0; tt < 4; ++tt) {
        half8 b0 = *reinterpret_cast<const half8*>(wt + (size_t)(tt * 16 + m) * DIM + q * 8);
        half8 b1 = *reinterpret_cast<const half8*>(wt + (size_t)(tt * 16 + m) * DIM + q * 8 + 32);
        floatx4 cfrag = {0.f, 0.f, 0.f, 0.f};
        cfrag = __builtin_amdgcn_mfma_f32_16x16x32_f16(a0, b0, cfrag, 0, 0, 0);
        cfrag = __builtin_amdgcn_mfma_f32_16x16x32_f16(a1, b1, cfrag, 0, 0, 0);
        acc4[tt] = cfrag;
    }

    #pragma unroll
    for (int r = 0; r < 4; ++r) {
        int row = q * 4 + r;
        int node = nb + lbase + row;
        if (node < N_NODES) {
            float inv = 1.0f / deg[node];
            #pragma unroll
            for (int tt = 0; tt < 4; ++tt) {
                float v = (acc4[tt][r] + bias[tt * 16 + m]) * inv;
                out[(size_t)node * DIM + tt * 16 + m] = fmaxf(v, 0.f);
            }
        }
    }
}

extern "C" void kernel_launch(void* const* d_in, const int* in_sizes, int n_in,
                              void* d_out, int out_size, void* d_ws, size_t ws_size,
                              hipStream_t stream) {
    const float* x        = (const float*)d_in[0];
    const float* weight   = (const float*)d_in[1];
    const float* bias     = (const float*)d_in[2];
    const float* node_deg = (const float*)d_in[3];
    const int*   edge_src = (const int*)d_in[4];
    const int*   edge_dst = (const int*)d_in[5];
    float* out = (float*)d_out;
    const int E = in_sizes[4];

    char* ws = (char*)d_ws;
    int*          cursor = (int*)(ws + WS_CURSOR);
    unsigned int* coarse = (unsigned int*)(ws + WS_COARSE);
    _Float16*     xh     = (_Float16*)(ws + WS_XH);
    _Float16*     wt     = (_Float16*)(ws + WS_WT);

    hipMemsetAsync(cursor, 0, CB * sizeof(int), stream);

    int pa = (E + EB - 1) / EB;               // 131 partition blocks
    prep_kernel<<<pa + 1563 + 1, 512, 0, stream>>>(
        x, weight, edge_src, edge_dst, cursor, coarse, xh, wt, E, pa);

    fused_kernel<<<784, 256, 0, stream>>>(
        xh, wt, bias, node_deg, cursor, coarse, out);
}